// Round 8
// baseline (662.255 us; speedup 1.0000x reference)
//
#include <hip/hip_runtime.h>

// out[b, n] = sum_k x[b,k] * w[n,k]
// B=8, S=1, K=4096, N=11008, fp32.
//
// Round-7 post-mortem: global_load_lds DMA pinned at the same ~2.3 TB/s as
// all VGPR-return variants -> per-CU outstanding-miss cap (~4 KB in flight
// per CU at ~1000 cy HBM latency ~= 2.4 TB/s device-wide). Last lever:
// eliminate all duty-cycle gaps so every wave has misses outstanding 100%
// of the time:
//  - ALL of x (128 KB) in LDS, staged once; ONE barrier in the kernel.
//  - 256 blocks x 1024 threads = 1 block/CU; 43 rows/block exact
//    (16 waves x 2 rows + waves 0..10 one extra row; NO redundant loads).
//  - explicit rolling pipeline: depth-4 per stream x 2 streams/wave
//    (8 nt loads = 8 KB in flight, steady-state vmcnt never below 6).
// Null/regress (dur_us >= 236) pre-registered as: per-CU miss cap is the
// roofline for this op.

#define BATCH 8
#define KDIM 4096
#define K4 (KDIM / 4)          // 1024 float4 per row
#define NDIM 11008
#define BLOCK 1024             // 16 waves, 1 block/CU (128 KB LDS)
#define RPB 43                 // 256 * 43 = 11008 exactly
#define NSTEP (K4 / 64)        // 16 K-steps of 1 KB per row

typedef float f4 __attribute__((ext_vector_type(4)));

__global__ __launch_bounds__(BLOCK)
void ActivationSparseLinear_4982162063725_kernel(const float* __restrict__ x,
                                                 const float* __restrict__ w,
                                                 float* __restrict__ out) {
    __shared__ f4 xs[BATCH * K4];          // 8192 f4 = 128 KB: ALL of x

    const int tid  = threadIdx.x;
    const int lane = tid & 63;
    const int wave = tid >> 6;

    const f4* xg4 = (const f4*)x;          // linear 8192 f4
    const f4* wg4 = (const f4*)w;          // [NDIM][K4]

    // Stage the whole activation once: 8 coalesced 1024-lane f4 loads.
#pragma unroll
    for (int p = 0; p < (BATCH * K4) / BLOCK; ++p)
        xs[p * BLOCK + tid] = xg4[p * BLOCK + tid];
    __syncthreads();                       // the only barrier

    const int nbase = blockIdx.x * RPB;
    const f4* wr0 = wg4 + (size_t)(nbase + 2 * wave + 0) * K4;
    const f4* wr1 = wg4 + (size_t)(nbase + 2 * wave + 1) * K4;

    float acc0[BATCH], acc1[BATCH], acc2[BATCH];
#pragma unroll
    for (int b = 0; b < BATCH; ++b) { acc0[b] = 0.f; acc1[b] = 0.f; acc2[b] = 0.f; }

    // ---- main phase: 2 row-streams, rolling depth-4 pipeline ----
    f4 wa[4], wb[4];
#pragma unroll
    for (int p = 0; p < 4; ++p) {
        wa[p] = __builtin_nontemporal_load(wr0 + p * 64 + lane);
        wb[p] = __builtin_nontemporal_load(wr1 + p * 64 + lane);
    }
#pragma unroll
    for (int s = 0; s < NSTEP; ++s) {
        const int kk = s * 64 + lane;
        const f4 w0 = wa[s & 3];           // waits vmcnt(6): oldest pair only
        const f4 w1 = wb[s & 3];
        if (s + 4 < NSTEP) {               // refill slot -> back to 8 in flight
            wa[s & 3] = __builtin_nontemporal_load(wr0 + (s + 4) * 64 + lane);
            wb[s & 3] = __builtin_nontemporal_load(wr1 + (s + 4) * 64 + lane);
        }
        f4 xv[BATCH];
#pragma unroll
        for (int b = 0; b < BATCH; ++b) xv[b] = xs[b * K4 + kk];  // conflict-free b128
#pragma unroll
        for (int b = 0; b < BATCH; ++b) {
            acc0[b] += w0[0] * xv[b][0] + w0[1] * xv[b][1]
                     + w0[2] * xv[b][2] + w0[3] * xv[b][3];
            acc1[b] += w1[0] * xv[b][0] + w1[1] * xv[b][1]
                     + w1[2] * xv[b][2] + w1[3] * xv[b][3];
        }
    }

    // ---- third row (waves 0..10): single stream, rolling depth-8 ----
    if (wave < RPB - 32) {
        const f4* wr2 = wg4 + (size_t)(nbase + 32 + wave) * K4;
        f4 wc[8];
#pragma unroll
        for (int p = 0; p < 8; ++p)
            wc[p] = __builtin_nontemporal_load(wr2 + p * 64 + lane);
#pragma unroll
        for (int s = 0; s < NSTEP; ++s) {
            const int kk = s * 64 + lane;
            const f4 w2 = wc[s & 7];
            if (s + 8 < NSTEP)
                wc[s & 7] = __builtin_nontemporal_load(wr2 + (s + 8) * 64 + lane);
            f4 xv[BATCH];
#pragma unroll
            for (int b = 0; b < BATCH; ++b) xv[b] = xs[b * K4 + kk];
#pragma unroll
            for (int b = 0; b < BATCH; ++b)
                acc2[b] += w2[0] * xv[b][0] + w2[1] * xv[b][1]
                         + w2[2] * xv[b][2] + w2[3] * xv[b][3];
        }
    }

    // ---- butterfly reductions + stores ----
#pragma unroll
    for (int b = 0; b < BATCH; ++b) {
        float v0 = acc0[b], v1 = acc1[b], v2 = acc2[b];
#pragma unroll
        for (int off = 32; off > 0; off >>= 1) {
            v0 += __shfl_xor(v0, off, 64);
            v1 += __shfl_xor(v1, off, 64);
            v2 += __shfl_xor(v2, off, 64);
        }
        acc0[b] = v0; acc1[b] = v1; acc2[b] = v2;
    }

    if (lane == 0) {
#pragma unroll
        for (int b = 0; b < BATCH; ++b) {
            out[(size_t)b * NDIM + nbase + 2 * wave + 0] = acc0[b];
            out[(size_t)b * NDIM + nbase + 2 * wave + 1] = acc1[b];
        }
        if (wave < RPB - 32)
#pragma unroll
            for (int b = 0; b < BATCH; ++b)
                out[(size_t)b * NDIM + nbase + 32 + wave] = acc2[b];
    }
}

extern "C" void kernel_launch(void* const* d_in, const int* in_sizes, int n_in,
                              void* d_out, int out_size, void* d_ws, size_t ws_size,
                              hipStream_t stream) {
    const float* x = (const float*)d_in[0];   // (8, 1, 4096) fp32
    const float* w = (const float*)d_in[1];   // (11008, 4096) fp32
    float* out = (float*)d_out;               // (8, 1, 11008) fp32

    dim3 grid(NDIM / RPB);                    // 256 blocks = 1 per CU
    ActivationSparseLinear_4982162063725_kernel<<<grid, BLOCK, 0, stream>>>(x, w, out);
}

// Round 9
// 464.608 us; speedup vs baseline: 1.4254x; 1.4254x over previous
//
#include <hip/hip_runtime.h>

// out[b, n] = sum_k x[b,k] * w[n,k]
// B=8, S=1, K=4096, N=11008, fp32.
//
// Round-8 post-mortem: the duty-cycle test was invalidated by spill --
// hipcc gives 1024-thread blocks a 64-VGPR budget (WRITE_SIZE 770 MB of
// scratch). HARD RULE: no 1024-thread blocks. This round re-runs the same
// theory in a spill-proof shape (256-thread precedents r0/r5/r6 all clean):
//  - 256 blocks x 256 threads = 1 block/CU, 43 rows/block exact balance.
//  - ALL of x (128 KB) DMA'd to LDS via global_load_lds (no VGPR cost),
//    ONE barrier total; afterwards vmcnt belongs exclusively to weights.
//  - each wave: 5 sequential row-pairs, rolling depth-4x2 nt-load pipeline
//    (8 KB in flight steady state); 3 waves stream 1 tail row at depth-8.
//    No barriers in the loop -> waves drift, bubbles decorrelate.
// Pre-registered: clean WRITE_SIZE + dur_us >= 236 -> allocating-read
// ceiling reached -> declare roofline.

#define BATCH 8
#define KDIM 4096
#define K4 (KDIM / 4)          // 1024 float4 per row
#define NDIM 11008
#define BLOCK 256              // 4 waves; plain launch_bounds, no VGPR trap
#define RPB 43                 // 256 * 43 = 11008 exactly
#define NSTEP (K4 / 64)        // 16 K-steps of 1 KB per row

typedef float f4 __attribute__((ext_vector_type(4)));

__device__ __forceinline__ void gld_lds16(const f4* g, f4* l) {
    // 16-byte async global->LDS DMA (pattern correctness-verified in r7).
    __builtin_amdgcn_global_load_lds(
        (const __attribute__((address_space(1))) void*)g,
        (__attribute__((address_space(3))) void*)l,
        16, 0, 0);
}

__global__ __launch_bounds__(BLOCK)
void ActivationSparseLinear_4982162063725_kernel(const float* __restrict__ x,
                                                 const float* __restrict__ w,
                                                 float* __restrict__ out) {
    __shared__ f4 xs[BATCH * K4];          // 8192 f4 = 128 KB: ALL of x

    const int tid  = threadIdx.x;
    const int lane = tid & 63;
    const int wave = tid >> 6;

    const f4* xg4 = (const f4*)x;          // linear 8192 f4 (L2-resident)
    const f4* wg4 = (const f4*)w;          // [NDIM][K4]

    // Stage all of x: 32 DMA issues/thread, contiguous per wave
    // (dest = wave-uniform base + lane*16 -- satisfies the LDS-dest rule).
#pragma unroll
    for (int p = 0; p < (BATCH * K4) / BLOCK; ++p)
        gld_lds16(xg4 + p * BLOCK + tid, &xs[p * BLOCK + tid]);
    __syncthreads();                       // the only barrier: x landed

    const int nbase = blockIdx.x * RPB;

    // ---- 5 row-pairs per wave: rows (8p+2*wave, 8p+2*wave+1) ----
    for (int p = 0; p < 5; ++p) {
        const int r0 = 8 * p + 2 * wave;
        const f4* wr0 = wg4 + (size_t)(nbase + r0 + 0) * K4;
        const f4* wr1 = wg4 + (size_t)(nbase + r0 + 1) * K4;

        float acc0[BATCH], acc1[BATCH];
#pragma unroll
        for (int b = 0; b < BATCH; ++b) { acc0[b] = 0.f; acc1[b] = 0.f; }

        f4 wa[4], wb[4];                   // rolling depth-4 per stream
#pragma unroll
        for (int q = 0; q < 4; ++q) {
            wa[q] = __builtin_nontemporal_load(wr0 + q * 64 + lane);
            wb[q] = __builtin_nontemporal_load(wr1 + q * 64 + lane);
        }
#pragma unroll
        for (int s = 0; s < NSTEP; ++s) {  // s compile-time -> s&3 static
            const f4 w0 = wa[s & 3];       // waits only the oldest pair
            const f4 w1 = wb[s & 3];
            if (s + 4 < NSTEP) {
                wa[s & 3] = __builtin_nontemporal_load(wr0 + (s + 4) * 64 + lane);
                wb[s & 3] = __builtin_nontemporal_load(wr1 + (s + 4) * 64 + lane);
            }
            const int kk = s * 64 + lane;
            f4 xv[BATCH];
#pragma unroll
            for (int b = 0; b < BATCH; ++b) xv[b] = xs[b * K4 + kk];  // b128, conflict-free
#pragma unroll
            for (int b = 0; b < BATCH; ++b) {
                acc0[b] += w0[0] * xv[b][0] + w0[1] * xv[b][1]
                         + w0[2] * xv[b][2] + w0[3] * xv[b][3];
                acc1[b] += w1[0] * xv[b][0] + w1[1] * xv[b][1]
                         + w1[2] * xv[b][2] + w1[3] * xv[b][3];
            }
        }

        // Reduce + store this pair (no barrier; waves drift freely).
#pragma unroll
        for (int b = 0; b < BATCH; ++b) {
            float v0 = acc0[b], v1 = acc1[b];
#pragma unroll
            for (int off = 32; off > 0; off >>= 1) {
                v0 += __shfl_xor(v0, off, 64);
                v1 += __shfl_xor(v1, off, 64);
            }
            if (lane == 0) {
                out[(size_t)b * NDIM + nbase + r0 + 0] = v0;
                out[(size_t)b * NDIM + nbase + r0 + 1] = v1;
            }
        }
    }

    // ---- tail: rows 40..42 on waves 0..2, single stream, depth-8 ----
    if (wave < RPB - 40) {
        const int rt = 40 + wave;
        const f4* wr2 = wg4 + (size_t)(nbase + rt) * K4;
        float acc2[BATCH];
#pragma unroll
        for (int b = 0; b < BATCH; ++b) acc2[b] = 0.f;

        f4 wc[8];
#pragma unroll
        for (int q = 0; q < 8; ++q)
            wc[q] = __builtin_nontemporal_load(wr2 + q * 64 + lane);
#pragma unroll
        for (int s = 0; s < NSTEP; ++s) {
            const f4 w2 = wc[s & 7];
            if (s + 8 < NSTEP)
                wc[s & 7] = __builtin_nontemporal_load(wr2 + (s + 8) * 64 + lane);
            const int kk = s * 64 + lane;
            f4 xv[BATCH];
#pragma unroll
            for (int b = 0; b < BATCH; ++b) xv[b] = xs[b * K4 + kk];
#pragma unroll
            for (int b = 0; b < BATCH; ++b)
                acc2[b] += w2[0] * xv[b][0] + w2[1] * xv[b][1]
                         + w2[2] * xv[b][2] + w2[3] * xv[b][3];
        }
#pragma unroll
        for (int b = 0; b < BATCH; ++b) {
            float v2 = acc2[b];
#pragma unroll
            for (int off = 32; off > 0; off >>= 1)
                v2 += __shfl_xor(v2, off, 64);
            if (lane == 0)
                out[(size_t)b * NDIM + nbase + rt] = v2;
        }
    }
}

extern "C" void kernel_launch(void* const* d_in, const int* in_sizes, int n_in,
                              void* d_out, int out_size, void* d_ws, size_t ws_size,
                              hipStream_t stream) {
    const float* x = (const float*)d_in[0];   // (8, 1, 4096) fp32
    const float* w = (const float*)d_in[1];   // (11008, 4096) fp32
    float* out = (float*)d_out;               // (8, 1, 11008) fp32

    dim3 grid(NDIM / RPB);                    // 256 blocks = 1 per CU
    ActivationSparseLinear_4982162063725_kernel<<<grid, BLOCK, 0, stream>>>(x, w, out);
}

// Round 10
// 267.892 us; speedup vs baseline: 2.4721x; 1.7343x over previous
//
#include <hip/hip_runtime.h>

// DIAGNOSTIC ROUND. out[b,n] = sum_k x[b,k]*w[n,k]; B=8,K=4096,N=11008 fp32.
//
// The fast kernels (r0/r2/r5/r6, ~75-86 us) never appear in the rocprof
// top-5 (ranked below the harness's 104-us poison fills), so their
// FETCH_SIZE/VALUBusy/Occupancy have NEVER been observed. Key unknown: r6
// restages x from global 4x per block x 1376 blocks; if those 32-KB stages
// miss L2 (weight stream floods it), x adds up to 176 MB hidden HBM reads
// -- exactly the gap between our 2.4 TB/s and the ~3.15 TB/s copy-read
// ceiling. This round: r6 VERBATIM + outer rep loop (weights read twice,
// acc scaled 0.5) to push the dispatch to ~300 us so it ranks in top-5.
// rep_stride (runtime 0) defeats load-CSE between passes.
// Decision tree: FETCH ~370 MB -> x innocent -> roofline next round.
//                FETCH >=430 MB -> x-thrash confirmed -> restructure x.

#define BATCH 8
#define KDIM 4096
#define K4 (KDIM / 4)         // 1024 float4 per weight row
#define NDIM 11008
#define KC 1024               // K-chunk staged into LDS (8*1024*4 = 32 KB)
#define KC4 (KC / 4)          // 256 float4 per batch per chunk
#define BLOCK 256             // 4 waves
#define ROWS_PER_WAVE 2
#define ROWS_PER_BLOCK 8      // 4 waves * 2 rows

typedef float f4 __attribute__((ext_vector_type(4)));

__global__ __launch_bounds__(BLOCK)
void ActivationSparseLinear_4982162063725_kernel(const float* __restrict__ x,
                                                 const float* __restrict__ w,
                                                 float* __restrict__ out,
                                                 int rep_stride) {
    __shared__ float4 xs[BATCH * KC4];   // 8 batches x 256 float4 = 32 KB

    const int tid  = threadIdx.x;
    const int lane = tid & 63;
    const int wave = tid >> 6;
    const int n0   = blockIdx.x * ROWS_PER_BLOCK + wave * ROWS_PER_WAVE;

    const float4* xg4 = (const float4*)x;     // [BATCH][K4]
    const f4* wg4 = (const f4*)w;             // [NDIM][K4]

    float acc[ROWS_PER_WAVE][BATCH];
#pragma unroll
    for (int r = 0; r < ROWS_PER_WAVE; ++r)
#pragma unroll
        for (int b = 0; b < BATCH; ++b) acc[r][b] = 0.0f;

#pragma unroll 1
    for (int rep = 0; rep < 2; ++rep) {
        // rep_stride is 0 at runtime but opaque to the compiler: the second
        // pass's weight addresses are formally distinct -> loads not CSE'd.
        const f4* wrow0 = wg4 + (size_t)(n0 + 0) * K4 + (size_t)rep * rep_stride;
        const f4* wrow1 = wg4 + (size_t)(n0 + 1) * K4 + (size_t)rep * rep_stride;

        for (int c = 0; c < KDIM / KC; ++c) {     // 4 chunks per pass
            // Stage x[:, c*KC .. c*KC+KC) into LDS (8 coalesced f4 loads).
#pragma unroll
            for (int j = 0; j < BATCH; ++j)
                xs[j * KC4 + tid] = xg4[j * K4 + c * KC4 + tid];
            __syncthreads();

            const int cb = c * KC4;

            // Burst-issue the chunk's weight loads (nt, as r6).
            f4 wa[4], wb[4];
#pragma unroll
            for (int i = 0; i < 4; ++i)
                wa[i] = __builtin_nontemporal_load(wrow0 + cb + i * 64 + lane);
#pragma unroll
            for (int i = 0; i < 4; ++i)
                wb[i] = __builtin_nontemporal_load(wrow1 + cb + i * 64 + lane);

            // Compute phase: x from LDS (lgkmcnt), weights drain on vmcnt.
#pragma unroll
            for (int i = 0; i < 4; ++i) {
                float4 xv[BATCH];
#pragma unroll
                for (int b = 0; b < BATCH; ++b)
                    xv[b] = xs[b * KC4 + i * 64 + lane];   // conflict-free b128

#pragma unroll
                for (int b = 0; b < BATCH; ++b) {
                    acc[0][b] += wa[i][0] * xv[b].x + wa[i][1] * xv[b].y
                               + wa[i][2] * xv[b].z + wa[i][3] * xv[b].w;
                    acc[1][b] += wb[i][0] * xv[b].x + wb[i][1] * xv[b].y
                               + wb[i][2] * xv[b].z + wb[i][3] * xv[b].w;
                }
            }
            __syncthreads();
        }
    }

    // Each sum was accumulated twice -> scale by 0.5, then butterfly-reduce.
#pragma unroll
    for (int r = 0; r < ROWS_PER_WAVE; ++r)
#pragma unroll
        for (int b = 0; b < BATCH; ++b) {
            float v = acc[r][b] * 0.5f;
#pragma unroll
            for (int off = 32; off > 0; off >>= 1)
                v += __shfl_xor(v, off, 64);
            acc[r][b] = v;
        }

    if (lane == 0) {
#pragma unroll
        for (int r = 0; r < ROWS_PER_WAVE; ++r)
#pragma unroll
            for (int b = 0; b < BATCH; ++b)
                out[(size_t)b * NDIM + n0 + r] = acc[r][b];
    }
}

extern "C" void kernel_launch(void* const* d_in, const int* in_sizes, int n_in,
                              void* d_out, int out_size, void* d_ws, size_t ws_size,
                              hipStream_t stream) {
    const float* x = (const float*)d_in[0];   // (8, 1, 4096) fp32
    const float* w = (const float*)d_in[1];   // (11008, 4096) fp32
    float* out = (float*)d_out;               // (8, 1, 11008) fp32

    dim3 grid(NDIM / ROWS_PER_BLOCK);         // 1376 blocks, exact fit
    ActivationSparseLinear_4982162063725_kernel<<<grid, BLOCK, 0, stream>>>(
        x, w, out, /*rep_stride=*/0);
}